// Round 2
// baseline (686.560 us; speedup 1.0000x reference)
//
#include <hip/hip_runtime.h>
#include <stdint.h>

#define NN 50000
#define NE 800000
#define STRIP 49   // ceil(NN/1024)

typedef unsigned int u32;
typedef uint16_t u16;

__device__ __forceinline__ float b2f(u16 u){ return __builtin_bit_cast(float, (u32)((u32)u << 16)); }
__device__ __forceinline__ float b2f_lo(u32 p){ return __builtin_bit_cast(float, p << 16); }
__device__ __forceinline__ float b2f_hi(u32 p){ return __builtin_bit_cast(float, p & 0xffff0000u); }
__device__ __forceinline__ u32 f2b_bits(float f){ u32 u = __builtin_bit_cast(u32, f); return (u + 0x7fffu + ((u >> 16) & 1u)) >> 16; }
__device__ __forceinline__ u16 f2b(float f){ return (u16)f2b_bits(f); }
__device__ __forceinline__ u32 packb(float lo, float hi){ return f2b_bits(lo) | (f2b_bits(hi) << 16); }

typedef __bf16 bf16x2 __attribute__((ext_vector_type(2)));
#if defined(__has_builtin)
#if __has_builtin(__builtin_amdgcn_fdot2_f32_bf16)
#define HAVE_DOT2_BUILTIN 1
#endif
#endif

#ifdef HAVE_DOT2_BUILTIN
__device__ __forceinline__ float dot2b(u32 a, u32 b, float c){
  return __builtin_amdgcn_fdot2_f32_bf16(__builtin_bit_cast(bf16x2, a),
                                         __builtin_bit_cast(bf16x2, b), c, false);
}
#else
__device__ __forceinline__ float dot2b(u32 a, u32 b, float c){
  c = fmaf(b2f_lo(a), b2f_lo(b), c);
  return fmaf(b2f_hi(a), b2f_hi(b), c);
}
#endif

// ---- MFMA plumbing ----
typedef __attribute__((ext_vector_type(8))) short short8;
typedef __attribute__((ext_vector_type(4))) float f32x4;
__device__ __forceinline__ f32x4 mf32(uint4 a, uint4 b, f32x4 c){
  return __builtin_amdgcn_mfma_f32_16x16x32_bf16(
      __builtin_bit_cast(short8, a), __builtin_bit_cast(short8, b), c, 0, 0, 0);
}

// pre-transposed weight layout offsets in u16 units (padded, zero-filled)
// NOTE: Wang_* blocks hold data at k in [16,32) (SH occupies the upper half of
// the fused [EA|SH] K=32 operand); W1_* keep data at k in [0,16).
#define OFF_WANG_V 0        // [128][40]
#define OFF_W1_V   5120     // [64][40]
#define OFF_WLIN_V 7680     // [128][136]
#define OFF_W2_V   25088    // [128][72]
#define OFF_WANG_K 34304    // [128][40]
#define OFF_W1_K   39424    // [64][40]
#define OFF_WLIN_K 41984    // [64][136]
#define OFF_W2_K   50688    // [64][72]
#define OFF_WOUT   55296    // [128][136]
#define OFF_WQD    72704    // [64][136]  (Wq @ blockdiag(Wdot))^T
#define WT_TOTAL   81408

__global__ __launch_bounds__(256) void zero_kernel(int* __restrict__ counts,
                                                   int* __restrict__ edge_ids)
{
  int i = blockIdx.x * 256 + threadIdx.x;
  if (i < NN) counts[i] = 0;
  if (i < NE) edge_ids[i] = 0;
}

// ---------------- one-time weight transpose/pad/bf16 prep
__global__ __launch_bounds__(256) void prep_w_kernel(
    const float* __restrict__ Wang_v, const float* __restrict__ W1_v,
    const float* __restrict__ Wlin_v, const float* __restrict__ W2_v,
    const float* __restrict__ Wang_k, const float* __restrict__ W1_k,
    const float* __restrict__ Wlin_k, const float* __restrict__ W2_k,
    const float* __restrict__ Wout, const float* __restrict__ Wq,
    const float* __restrict__ Wdot,
    u16* __restrict__ wt)
{
  int idx = blockIdx.x * 256 + threadIdx.x;
  if (idx >= WT_TOTAL) return;
  float val = 0.f;
  if (idx < OFF_W1_V) {
    int l = idx - OFF_WANG_V, n = l / 40, k = l % 40;
    if (k >= 16 && k < 32) val = Wang_v[n * 16 + (k - 16)];
  } else if (idx < OFF_WLIN_V) {
    int l = idx - OFF_W1_V, n = l / 40, k = l % 40;
    if (k < 16) val = W1_v[k * 64 + n];
  } else if (idx < OFF_W2_V) {
    int l = idx - OFF_WLIN_V, n = l / 136, k = l % 136;
    if (k < 128) val = Wlin_v[k * 128 + n];
  } else if (idx < OFF_WANG_K) {
    int l = idx - OFF_W2_V, n = l / 72, k = l % 72;
    if (k < 64) val = W2_v[k * 128 + n];
  } else if (idx < OFF_W1_K) {
    int l = idx - OFF_WANG_K, n = l / 40, k = l % 40;
    if (k >= 16 && k < 32) val = Wang_k[n * 16 + (k - 16)];
  } else if (idx < OFF_WLIN_K) {
    int l = idx - OFF_W1_K, n = l / 40, k = l % 40;
    if (k < 16) val = W1_k[k * 64 + n];
  } else if (idx < OFF_W2_K) {
    int l = idx - OFF_WLIN_K, n = l / 136, k = l % 136;
    if (k < 128) val = Wlin_k[k * 64 + n];
  } else if (idx < OFF_WOUT) {
    int l = idx - OFF_W2_K, n = l / 72, k = l % 72;
    if (k < 64) val = W2_k[k * 64 + n];
  } else if (idx < OFF_WQD) {                // WoutT: B^T[n][k] = Wout[k*128+n]
    int l = idx - OFF_WOUT, n = l / 136, k = l % 136;
    if (k < 128) val = Wout[k * 128 + n];
  } else {                                   // WqdT[n][k] = sum_i Wq[k,h*8+i]*Wdot[i,r]
    int l = idx - OFF_WQD, n = l / 136, k = l % 136;
    if (k < 128) {
      int h = n >> 3, r = n & 7;
      float s = 0.f;
#pragma unroll
      for (int i = 0; i < 8; ++i) s += Wq[k * 64 + h * 8 + i] * Wdot[i * 8 + r];
      val = s;
    }
  }
  wt[idx] = f2b(val);
}

// ---------------- qw = node_attr @ Wqd, MFMA, 64 nodes/block
__global__ __launch_bounds__(256) void qw_kernel(const float* __restrict__ node_attr,
                                                 const u16* __restrict__ wt,
                                                 u16* __restrict__ qw)
{
  __shared__ __align__(16) u16 sX[64 * 136];
  uint4* sX4 = (uint4*)sX;
  u32* sX32 = (u32*)sX;
  const uint4* wt4 = (const uint4*)wt;
  const int tid = threadIdx.x, wv = tid >> 6, lane = tid & 63, lq = lane >> 4, ln = lane & 15;
  const int n0 = blockIdx.x * 64;
  // B-fragments for cols wv*16+ln
  uint4 rB[4];
#pragma unroll
  for (int ks = 0; ks < 4; ++ks) rB[ks] = wt4[9088 + (wv * 16 + ln) * 17 + ks * 4 + lq];
  // stage X: 64 rows x 128 cols fp32 -> bf16, pitch 136 u16
  {
    int row = tid >> 2, q4 = tid & 3;
    int n = n0 + row;
    bool valid = n < NN;
    const float4* xp = (const float4*)(node_attr + (size_t)(valid ? n : 0) * 128);
#pragma unroll
    for (int i = 0; i < 8; ++i) {
      float4 v = valid ? xp[q4 * 8 + i] : make_float4(0.f, 0.f, 0.f, 0.f);
      sX32[row * 68 + (q4 * 8 + i) * 2]     = packb(v.x, v.y);
      sX32[row * 68 + (q4 * 8 + i) * 2 + 1] = packb(v.z, v.w);
    }
  }
  __syncthreads();
  const f32x4 z4 = {0.f, 0.f, 0.f, 0.f};
  int col = wv * 16 + ln;
#pragma unroll
  for (int et = 0; et < 4; ++et) {
    f32x4 acc = z4;
#pragma unroll
    for (int ks = 0; ks < 4; ++ks) acc = mf32(sX4[(et * 16 + ln) * 17 + ks * 4 + lq], rB[ks], acc);
#pragma unroll
    for (int r = 0; r < 4; ++r) {
      int rr = n0 + et * 16 + lq * 4 + r;
      if (rr < NN) qw[(size_t)rr * 64 + col] = f2b(acc[r]);
    }
  }
}

// ---------------- fused MFMA conv (K pass then V pass sharing LDS) + alpha.
// LDS halved vs the single-pass layout (31744 B) -> 4-5 blocks/CU instead of 2.
__global__ __launch_bounds__(256, 4) void conv_fused_kernel(
    const float* __restrict__ node_attr, const float* __restrict__ edge_attr,
    const float* __restrict__ edge_sh, const int* __restrict__ edge_index,
    const float* __restrict__ b1v, const float* __restrict__ b1k,
    const u16* __restrict__ wt, const u16* __restrict__ qw,
    u16* __restrict__ v_out, float* __restrict__ alpha)
{
  __shared__ __align__(16) u16 sC[64 * 40];    // fused [EA(16)|SH(16)|pad(8)] per edge
  __shared__ __align__(16) u16 sT[64 * 136];   // T buffer: K pass, then V pass, then v staging
  __shared__ __align__(16) u16 sH[64 * 72];    // H buffer: K pass, then V pass, then k staging
  uint4* sC4 = (uint4*)sC; u32* sC32 = (u32*)sC;
  uint4* sT4 = (uint4*)sT;
  uint4* sH4 = (uint4*)sH;
  const uint4* wt4 = (const uint4*)wt;

  const int tid = threadIdx.x;
  const int wv = tid >> 6, lane = tid & 63, lq = lane >> 4, ln = lane & 15;
  const int e0 = blockIdx.x * 64;
  const int nA = wv * 16 + ln, nB = (wv + 4) * 16 + ln;

  int srcs[4][4];
#pragma unroll
  for (int et = 0; et < 4; ++et)
#pragma unroll
    for (int r = 0; r < 4; ++r) {
      int s = edge_index[e0 + et * 16 + lq * 4 + r];
      if ((u32)s >= NN) s = 0;
      srcs[et][r] = s;
    }
  float xf[2][4][4];
#pragma unroll
  for (int c = 0; c < 2; ++c) {
    int col = (wv + 4 * c) * 16 + ln;
#pragma unroll
    for (int et = 0; et < 4; ++et)
#pragma unroll
      for (int r = 0; r < 4; ++r)
        xf[c][et][r] = node_attr[(size_t)srcs[et][r] * 128 + col];
  }

  {
    int r = tid >> 2, kq = tid & 3;
    float4 ea = ((const float4*)(edge_attr + (size_t)(e0 + r) * 16))[kq];
    sC32[r * 20 + kq * 2]     = packb(ea.x, ea.y);
    sC32[r * 20 + kq * 2 + 1] = packb(ea.z, ea.w);
    float4 sh = ((const float4*)(edge_sh + (size_t)(e0 + r) * 16))[kq];
    sC32[r * 20 + 8 + kq * 2]     = packb(sh.x, sh.y);
    sC32[r * 20 + 8 + kq * 2 + 1] = packb(sh.z, sh.w);
  }
  __syncthreads();   // S1

  const f32x4 z4 = {0.f, 0.f, 0.f, 0.f};
  u32 kp[4][2];      // packed bf16 k results (rows r0r1, r2r3)
  // ================= K pass =================
  {
    uint4 rW1K    = wt4[4928 + nA * 5 + lq];
    uint4 rWangK0 = wt4[4288 + nA * 5 + lq];
    uint4 rWangK1 = wt4[4288 + nB * 5 + lq];
    float biasK = b1k[nA];
#pragma unroll
    for (int et = 0; et < 4; ++et) {
      uint4 aC = sC4[(et * 16 + ln) * 5 + lq];
      f32x4 h  = mf32(aC, rW1K, z4);       // EA half (Wang rows zero there)
      f32x4 t0 = mf32(aC, rWangK0, z4);    // SH half (W1 rows zero there)
      f32x4 t1 = mf32(aC, rWangK1, z4);
      int rowb = et * 16 + lq * 4;
#pragma unroll
      for (int r = 0; r < 4; ++r) {
        sH[(rowb + r) * 72 + nA]  = f2b(fmaxf(h[r] + biasK, 0.f));
        sT[(rowb + r) * 136 + nA] = f2b(t0[r] * xf[0][et][r]);
        sT[(rowb + r) * 136 + nB] = f2b(t1[r] * xf[1][et][r]);
      }
    }
  }
  __syncthreads();  // S2
  {
    uint4 rWlinK[4], rW2K[2];
#pragma unroll
    for (int ks = 0; ks < 4; ++ks) rWlinK[ks] = wt4[5248 + nA * 17 + ks * 4 + lq];
#pragma unroll
    for (int ks = 0; ks < 2; ++ks) rW2K[ks] = wt4[6336 + nA * 9 + ks * 4 + lq];
#pragma unroll
    for (int et = 0; et < 4; ++et) {
      int ar = et * 16 + ln;
      f32x4 a1 = z4, a2 = z4;
#pragma unroll
      for (int ks = 0; ks < 4; ++ks) a1 = mf32(sT4[ar * 17 + ks * 4 + lq], rWlinK[ks], a1);
#pragma unroll
      for (int ks = 0; ks < 2; ++ks) a2 = mf32(sH4[ar * 9 + ks * 4 + lq], rW2K[ks], a2);
      kp[et][0] = packb(a1[0] * a2[0], a1[1] * a2[1]);
      kp[et][1] = packb(a1[2] * a2[2], a1[3] * a2[3]);
    }
  }
  __syncthreads();  // S3 (sT/sH free for V pass)
  // ================= V pass =================
  u32 vp[2][4][2];   // packed bf16 v results, both column halves
  {
    uint4 rW1V    = wt4[640 + nA * 5 + lq];
    uint4 rWangV0 = wt4[nA * 5 + lq];
    uint4 rWangV1 = wt4[nB * 5 + lq];
    float biasV = b1v[nA];
#pragma unroll
    for (int et = 0; et < 4; ++et) {
      uint4 aC = sC4[(et * 16 + ln) * 5 + lq];
      f32x4 h  = mf32(aC, rW1V, z4);
      f32x4 t0 = mf32(aC, rWangV0, z4);
      f32x4 t1 = mf32(aC, rWangV1, z4);
      int rowb = et * 16 + lq * 4;
#pragma unroll
      for (int r = 0; r < 4; ++r) {
        sH[(rowb + r) * 72 + nA]  = f2b(fmaxf(h[r] + biasV, 0.f));
        sT[(rowb + r) * 136 + nA] = f2b(t0[r] * xf[0][et][r]);
        sT[(rowb + r) * 136 + nB] = f2b(t1[r] * xf[1][et][r]);
      }
    }
  }
  __syncthreads();  // S4
  {
    uint4 rWlinV0[4], rWlinV1[4], rW2V0[2], rW2V1[2];
#pragma unroll
    for (int ks = 0; ks < 4; ++ks) {
      rWlinV0[ks] = wt4[960 + nA * 17 + ks * 4 + lq];
      rWlinV1[ks] = wt4[960 + nB * 17 + ks * 4 + lq];
    }
#pragma unroll
    for (int ks = 0; ks < 2; ++ks) {
      rW2V0[ks] = wt4[3136 + nA * 9 + ks * 4 + lq];
      rW2V1[ks] = wt4[3136 + nB * 9 + ks * 4 + lq];
    }
#pragma unroll
    for (int et = 0; et < 4; ++et) {
      int ar = et * 16 + ln;
      f32x4 a10 = z4, a11 = z4, a20 = z4, a21 = z4;
#pragma unroll
      for (int ks = 0; ks < 4; ++ks) {
        uint4 t = sT4[ar * 17 + ks * 4 + lq];
        a10 = mf32(t, rWlinV0[ks], a10);
        a11 = mf32(t, rWlinV1[ks], a11);
      }
#pragma unroll
      for (int ks = 0; ks < 2; ++ks) {
        uint4 hf = sH4[ar * 9 + ks * 4 + lq];
        a20 = mf32(hf, rW2V0[ks], a20);
        a21 = mf32(hf, rW2V1[ks], a21);
      }
      vp[0][et][0] = packb(a10[0] * a20[0], a10[1] * a20[1]);
      vp[0][et][1] = packb(a10[2] * a20[2], a10[3] * a20[3]);
      vp[1][et][0] = packb(a11[0] * a21[0], a11[1] * a21[1]);
      vp[1][et][1] = packb(a11[2] * a21[2], a11[3] * a21[3]);
    }
  }
  __syncthreads();  // S5
#pragma unroll
  for (int et = 0; et < 4; ++et) {
    int rowb = et * 16 + lq * 4;
#pragma unroll
    for (int r = 0; r < 4; ++r) {
      u32 kv = kp[et][r >> 1];
      u32 v0 = vp[0][et][r >> 1];
      u32 v1 = vp[1][et][r >> 1];
      sH[(rowb + r) * 72 + nA]  = (r & 1) ? (u16)(kv >> 16) : (u16)kv;
      sT[(rowb + r) * 136 + nA] = (r & 1) ? (u16)(v0 >> 16) : (u16)v0;
      sT[(rowb + r) * 136 + nB] = (r & 1) ? (u16)(v1 >> 16) : (u16)v1;
    }
  }
  __syncthreads();  // S6
  {
    int row = tid >> 2, seg = tid & 3;
    uint4* gp = (uint4*)(v_out + (size_t)(e0 + row) * 128);
#pragma unroll
    for (int i = 0; i < 4; ++i) gp[seg * 4 + i] = sT4[row * 17 + seg * 4 + i];
  }
  {
    int el = tid >> 2, p = tid & 3;
    int dq = edge_index[NE + e0 + el]; if ((u32)dq >= NN) dq = 0;
    const uint4* qptr = (const uint4*)(qw + (size_t)dq * 64 + p * 16);
    uint4 q0 = qptr[0], q1 = qptr[1];
    uint4 k0 = sH4[el * 9 + p * 2];
    uint4 k1 = sH4[el * 9 + p * 2 + 1];
    float a0 = 0.f, a1 = 0.f;
    a0 = dot2b(q0.x, k0.x, a0); a0 = dot2b(q0.y, k0.y, a0);
    a0 = dot2b(q0.z, k0.z, a0); a0 = dot2b(q0.w, k0.w, a0);
    a1 = dot2b(q1.x, k1.x, a1); a1 = dot2b(q1.y, k1.y, a1);
    a1 = dot2b(q1.z, k1.z, a1); a1 = dot2b(q1.w, k1.w, a1);
    ((float2*)(alpha + (size_t)(e0 + el) * 8))[p] = make_float2(a0, a1);
  }
}

// ---------------- CSR build
__global__ __launch_bounds__(256) void count_kernel(const int* __restrict__ edge_index,
                                                    int* __restrict__ counts)
{
  int e = blockIdx.x * 256 + threadIdx.x;
  if (e < NE) { int d = edge_index[NE + e]; if ((u32)d >= NN) d = 0; atomicAdd(&counts[d], 1); }
}

__global__ __launch_bounds__(1024) void scan_kernel(const int* __restrict__ counts,
                                                    int* __restrict__ row_ptr,
                                                    int* __restrict__ cursor)
{
  __shared__ int s[1024];
  int tid = threadIdx.x;
  int base = tid * STRIP;
  int sum = 0;
  for (int i = 0; i < STRIP; ++i) { int idx = base + i; sum += (idx < NN) ? counts[idx] : 0; }
  s[tid] = sum;
  __syncthreads();
  for (int off = 1; off < 1024; off <<= 1) {
    int v = s[tid];
    int add = (tid >= off) ? s[tid - off] : 0;
    __syncthreads();
    s[tid] = v + add;
    __syncthreads();
  }
  int running = (tid == 0) ? 0 : s[tid - 1];
  for (int i = 0; i < STRIP; ++i) {
    int idx = base + i;
    if (idx < NN) { row_ptr[idx] = running; cursor[idx] = running; running += counts[idx]; }
  }
  if (tid == 1023) row_ptr[NN] = running;
}

__global__ __launch_bounds__(256) void fill_kernel(const int* __restrict__ edge_index,
                                                   int* __restrict__ cursor,
                                                   int* __restrict__ edge_ids)
{
  int e = blockIdx.x * 256 + threadIdx.x;
  if (e < NE) {
    int dst = edge_index[NE + e]; if ((u32)dst >= NN) dst = 0;
    int pos = atomicAdd(&cursor[dst], 1);
    if ((u32)pos < NE) edge_ids[pos] = e;
  }
}

// ---------------- per-node single-pass online softmax + V gather (u32 loads,
// 4x unrolled) + MFMA @Wout epilogue. One wave per node, 16 nodes per block.
#define OUPD(aa, ww)                                                   \
  { float mn = fmaxf(m, (aa));                                         \
    float sc = __expf(m - mn);                                         \
    float pw = __expf((aa) - mn);                                      \
    l = l * sc + pw;                                                   \
    accA = accA * sc + pw * b2f_lo(ww);                                \
    accB = accB * sc + pw * b2f_hi(ww);                                \
    m = mn; }

__global__ __launch_bounds__(256) void out_kernel(
    const int* __restrict__ row_ptr, const int* __restrict__ edge_ids,
    const float* __restrict__ alpha, const u16* __restrict__ v_e,
    const u16* __restrict__ wt, float* __restrict__ out)
{
  __shared__ __align__(16) u16 sAgg[16 * 136];
  u32* sAgg32 = (u32*)sAgg;
  uint4* sAgg4 = (uint4*)sAgg;
  const uint4* wt4 = (const uint4*)wt;
  const u32* v32 = (const u32*)v_e;
  const int tid = threadIdx.x, wv = tid >> 6, lane = tid & 63, lq = lane >> 4, ln = lane & 15;
  const f32x4 z4 = {0.f, 0.f, 0.f, 0.f};
  uint4 rWT[2][4];
#pragma unroll
  for (int c = 0; c < 2; ++c) {
    int n = (wv * 2 + c) * 16 + ln;
#pragma unroll
    for (int ks = 0; ks < 4; ++ks) rWT[c][ks] = wt4[6912 + n * 17 + ks * 4 + lq];
  }
  const int hh = lane >> 3;   // head of cols {2*lane, 2*lane+1}
  const int grp = blockIdx.x;
#pragma unroll 1
  for (int i = 0; i < 4; ++i) {
    int n = grp * 16 + wv * 4 + i;
    int beg = row_ptr[n], end = row_ptr[n + 1];
    if (beg < 0) beg = 0; if (beg > NE) beg = NE;
    if (end < beg) end = beg; if (end > NE) end = NE;
    int deg = end - beg;
    float m = -3.0e38f, l = 0.f, accA = 0.f, accB = 0.f;
    int j = 0;
#pragma unroll 1
    for (; j + 4 <= deg; j += 4) {
      int e0 = edge_ids[beg + j],     e1 = edge_ids[beg + j + 1];
      int e2 = edge_ids[beg + j + 2], e3 = edge_ids[beg + j + 3];
      if ((u32)e0 >= NE) e0 = 0; if ((u32)e1 >= NE) e1 = 0;
      if ((u32)e2 >= NE) e2 = 0; if ((u32)e3 >= NE) e3 = 0;
      float a0 = alpha[(size_t)e0 * 8 + hh]; u32 w0 = v32[(size_t)e0 * 64 + lane];
      float a1 = alpha[(size_t)e1 * 8 + hh]; u32 w1 = v32[(size_t)e1 * 64 + lane];
      float a2 = alpha[(size_t)e2 * 8 + hh]; u32 w2 = v32[(size_t)e2 * 64 + lane];
      float a3 = alpha[(size_t)e3 * 8 + hh]; u32 w3 = v32[(size_t)e3 * 64 + lane];
      OUPD(a0, w0); OUPD(a1, w1); OUPD(a2, w2); OUPD(a3, w3);
    }
#pragma unroll 1
    for (; j < deg; ++j) {
      int e = edge_ids[beg + j]; if ((u32)e >= NE) e = 0;
      float a = alpha[(size_t)e * 8 + hh]; u32 w = v32[(size_t)e * 64 + lane];
      OUPD(a, w);
    }
    float inv = (l > 0.f) ? (1.f / l) : 0.f;
    accA *= inv; accB *= inv;
    sAgg32[(wv * 4 + i) * 68 + lane] = packb(accA, accB);
  }
  __syncthreads();
#pragma unroll
  for (int c = 0; c < 2; ++c) {
    f32x4 acc = z4;
#pragma unroll
    for (int ks = 0; ks < 4; ++ks) acc = mf32(sAgg4[ln * 17 + ks * 4 + lq], rWT[c][ks], acc);
    int col = (wv * 2 + c) * 16 + ln;
#pragma unroll
    for (int r = 0; r < 4; ++r)
      out[(size_t)(grp * 16 + lq * 4 + r) * 128 + col] = acc[r];
  }
}

extern "C" void kernel_launch(void* const* d_in, const int* in_sizes, int n_in,
                              void* d_out, int out_size, void* d_ws, size_t ws_size,
                              hipStream_t stream)
{
  const float* node_attr = (const float*)d_in[0];
  const float* edge_attr = (const float*)d_in[1];
  const float* edge_sh   = (const float*)d_in[2];
  const float* Wq        = (const float*)d_in[3];
  const float* Wang_k    = (const float*)d_in[4];
  const float* Wlin_k    = (const float*)d_in[5];
  const float* W1k       = (const float*)d_in[6];
  const float* b1k       = (const float*)d_in[7];
  const float* W2k       = (const float*)d_in[8];
  const float* Wang_v    = (const float*)d_in[9];
  const float* Wlin_v    = (const float*)d_in[10];
  const float* W1v       = (const float*)d_in[11];
  const float* b1v       = (const float*)d_in[12];
  const float* W2v       = (const float*)d_in[13];
  const float* Wdot      = (const float*)d_in[14];
  const float* Wout      = (const float*)d_in[15];
  const int* edge_index  = (const int*)d_in[16];
  float* out = (float*)d_out;

  char* ws = (char*)d_ws;
  u16*   v_e      = (u16*)(ws + 0);                 // E*128*2  = 204,800,000
  float* alpha    = (float*)(ws + 204800000);       // E*8*4    =  25,600,000
  u16*   qw       = (u16*)(ws + 230400000);         // N*64*2   =   6,400,000
  int*   counts   = (int*)(ws + 236800000);         // 200,064
  int*   row_ptr  = (int*)(ws + 237000064);         // 200,064
  int*   cursor   = (int*)(ws + 237200128);         // 200,064
  int*   edge_ids = (int*)(ws + 237400192);         // 3,200,000
  u16*   wt       = (u16*)(ws + 240600192);         // 162,816 -> total 240,763,008

  zero_kernel<<<dim3((NE + 255) / 256), dim3(256), 0, stream>>>(counts, edge_ids);
  prep_w_kernel<<<dim3((WT_TOTAL + 255) / 256), dim3(256), 0, stream>>>(
      Wang_v, W1v, Wlin_v, W2v, Wang_k, W1k, Wlin_k, W2k, Wout, Wq, Wdot, wt);
  qw_kernel<<<dim3((NN + 63) / 64), dim3(256), 0, stream>>>(node_attr, wt, qw);
  conv_fused_kernel<<<dim3(NE / 64), dim3(256), 0, stream>>>(
      node_attr, edge_attr, edge_sh, edge_index, b1v, b1k, wt, qw, v_e, alpha);
  count_kernel<<<dim3((NE + 255) / 256), dim3(256), 0, stream>>>(edge_index, counts);
  scan_kernel<<<dim3(1), dim3(1024), 0, stream>>>(counts, row_ptr, cursor);
  fill_kernel<<<dim3((NE + 255) / 256), dim3(256), 0, stream>>>(edge_index, cursor, edge_ids);
  out_kernel<<<dim3(3125), dim3(256), 0, stream>>>(row_ptr, edge_ids, alpha, v_e, wt, out);
}

// Round 3
// 685.119 us; speedup vs baseline: 1.0021x; 1.0021x over previous
//
#include <hip/hip_runtime.h>
#include <stdint.h>

#define NN 50000
#define NE 800000
#define STRIP 49   // ceil(NN/1024)

typedef unsigned int u32;
typedef uint16_t u16;

__device__ __forceinline__ float b2f(u16 u){ return __builtin_bit_cast(float, (u32)((u32)u << 16)); }
__device__ __forceinline__ float b2f_lo(u32 p){ return __builtin_bit_cast(float, p << 16); }
__device__ __forceinline__ float b2f_hi(u32 p){ return __builtin_bit_cast(float, p & 0xffff0000u); }
__device__ __forceinline__ u32 f2b_bits(float f){ u32 u = __builtin_bit_cast(u32, f); return (u + 0x7fffu + ((u >> 16) & 1u)) >> 16; }
__device__ __forceinline__ u16 f2b(float f){ return (u16)f2b_bits(f); }
__device__ __forceinline__ u32 packb(float lo, float hi){ return f2b_bits(lo) | (f2b_bits(hi) << 16); }

typedef __bf16 bf16x2 __attribute__((ext_vector_type(2)));
#if defined(__has_builtin)
#if __has_builtin(__builtin_amdgcn_fdot2_f32_bf16)
#define HAVE_DOT2_BUILTIN 1
#endif
#endif

#ifdef HAVE_DOT2_BUILTIN
__device__ __forceinline__ float dot2b(u32 a, u32 b, float c){
  return __builtin_amdgcn_fdot2_f32_bf16(__builtin_bit_cast(bf16x2, a),
                                         __builtin_bit_cast(bf16x2, b), c, false);
}
#else
__device__ __forceinline__ float dot2b(u32 a, u32 b, float c){
  c = fmaf(b2f_lo(a), b2f_lo(b), c);
  return fmaf(b2f_hi(a), b2f_hi(b), c);
}
#endif

// ---- MFMA plumbing ----
typedef __attribute__((ext_vector_type(8))) short short8;
typedef __attribute__((ext_vector_type(4))) float f32x4;
__device__ __forceinline__ f32x4 mf32(uint4 a, uint4 b, f32x4 c){
  return __builtin_amdgcn_mfma_f32_16x16x32_bf16(
      __builtin_bit_cast(short8, a), __builtin_bit_cast(short8, b), c, 0, 0, 0);
}

// pre-transposed weight layout offsets in u16 units (padded, zero-filled)
// Wang_* blocks hold data at k in [16,32) (SH = upper half of fused [EA|SH]
// K=32 operand); W1_* keep data at k in [0,16).
#define OFF_WANG_V 0        // [128][40]
#define OFF_W1_V   5120     // [64][40]
#define OFF_WLIN_V 7680     // [128][136]
#define OFF_W2_V   25088    // [128][72]
#define OFF_WANG_K 34304    // [128][40]
#define OFF_W1_K   39424    // [64][40]
#define OFF_WLIN_K 41984    // [64][136]
#define OFF_W2_K   50688    // [64][72]
#define OFF_WOUT   55296    // [128][136]
#define OFF_WQD    72704    // [64][136]  (Wq @ blockdiag(Wdot))^T
#define WT_TOTAL   81408

__global__ __launch_bounds__(256) void zero_kernel(int* __restrict__ counts,
                                                   int* __restrict__ edge_ids)
{
  int i = blockIdx.x * 256 + threadIdx.x;
  if (i < NN) counts[i] = 0;
  if (i < NE) edge_ids[i] = 0;
}

// ---------------- one-time weight transpose/pad/bf16 prep
__global__ __launch_bounds__(256) void prep_w_kernel(
    const float* __restrict__ Wang_v, const float* __restrict__ W1_v,
    const float* __restrict__ Wlin_v, const float* __restrict__ W2_v,
    const float* __restrict__ Wang_k, const float* __restrict__ W1_k,
    const float* __restrict__ Wlin_k, const float* __restrict__ W2_k,
    const float* __restrict__ Wout, const float* __restrict__ Wq,
    const float* __restrict__ Wdot,
    u16* __restrict__ wt)
{
  int idx = blockIdx.x * 256 + threadIdx.x;
  if (idx >= WT_TOTAL) return;
  float val = 0.f;
  if (idx < OFF_W1_V) {
    int l = idx - OFF_WANG_V, n = l / 40, k = l % 40;
    if (k >= 16 && k < 32) val = Wang_v[n * 16 + (k - 16)];
  } else if (idx < OFF_WLIN_V) {
    int l = idx - OFF_W1_V, n = l / 40, k = l % 40;
    if (k < 16) val = W1_v[k * 64 + n];
  } else if (idx < OFF_W2_V) {
    int l = idx - OFF_WLIN_V, n = l / 136, k = l % 136;
    if (k < 128) val = Wlin_v[k * 128 + n];
  } else if (idx < OFF_WANG_K) {
    int l = idx - OFF_W2_V, n = l / 72, k = l % 72;
    if (k < 64) val = W2_v[k * 128 + n];
  } else if (idx < OFF_W1_K) {
    int l = idx - OFF_WANG_K, n = l / 40, k = l % 40;
    if (k >= 16 && k < 32) val = Wang_k[n * 16 + (k - 16)];
  } else if (idx < OFF_WLIN_K) {
    int l = idx - OFF_W1_K, n = l / 40, k = l % 40;
    if (k < 16) val = W1_k[k * 64 + n];
  } else if (idx < OFF_W2_K) {
    int l = idx - OFF_WLIN_K, n = l / 136, k = l % 136;
    if (k < 128) val = Wlin_k[k * 64 + n];
  } else if (idx < OFF_WOUT) {
    int l = idx - OFF_W2_K, n = l / 72, k = l % 72;
    if (k < 64) val = W2_k[k * 64 + n];
  } else if (idx < OFF_WQD) {                // WoutT: B^T[n][k] = Wout[k*128+n]
    int l = idx - OFF_WOUT, n = l / 136, k = l % 136;
    if (k < 128) val = Wout[k * 128 + n];
  } else {                                   // WqdT[n][k] = sum_i Wq[k,h*8+i]*Wdot[i,r]
    int l = idx - OFF_WQD, n = l / 136, k = l % 136;
    if (k < 128) {
      int h = n >> 3, r = n & 7;
      float s = 0.f;
#pragma unroll
      for (int i = 0; i < 8; ++i) s += Wq[k * 64 + h * 8 + i] * Wdot[i * 8 + r];
      val = s;
    }
  }
  wt[idx] = f2b(val);
}

// ---------------- qw = node_attr @ Wqd, MFMA, 64 nodes/block
__global__ __launch_bounds__(256) void qw_kernel(const float* __restrict__ node_attr,
                                                 const u16* __restrict__ wt,
                                                 u16* __restrict__ qw)
{
  __shared__ __align__(16) u16 sX[64 * 136];
  uint4* sX4 = (uint4*)sX;
  u32* sX32 = (u32*)sX;
  const uint4* wt4 = (const uint4*)wt;
  const int tid = threadIdx.x, wv = tid >> 6, lane = tid & 63, lq = lane >> 4, ln = lane & 15;
  const int n0 = blockIdx.x * 64;
  uint4 rB[4];
#pragma unroll
  for (int ks = 0; ks < 4; ++ks) rB[ks] = wt4[9088 + (wv * 16 + ln) * 17 + ks * 4 + lq];
  {
    int row = tid >> 2, q4 = tid & 3;
    int n = n0 + row;
    bool valid = n < NN;
    const float4* xp = (const float4*)(node_attr + (size_t)(valid ? n : 0) * 128);
#pragma unroll
    for (int i = 0; i < 8; ++i) {
      float4 v = valid ? xp[q4 * 8 + i] : make_float4(0.f, 0.f, 0.f, 0.f);
      sX32[row * 68 + (q4 * 8 + i) * 2]     = packb(v.x, v.y);
      sX32[row * 68 + (q4 * 8 + i) * 2 + 1] = packb(v.z, v.w);
    }
  }
  __syncthreads();
  const f32x4 z4 = {0.f, 0.f, 0.f, 0.f};
  int col = wv * 16 + ln;
#pragma unroll
  for (int et = 0; et < 4; ++et) {
    f32x4 acc = z4;
#pragma unroll
    for (int ks = 0; ks < 4; ++ks) acc = mf32(sX4[(et * 16 + ln) * 17 + ks * 4 + lq], rB[ks], acc);
#pragma unroll
    for (int r = 0; r < 4; ++r) {
      int rr = n0 + et * 16 + lq * 4 + r;
      if (rr < NN) qw[(size_t)rr * 64 + col] = f2b(acc[r]);
    }
  }
}

// ---------------- fused MFMA conv (single pass, v and k together) + alpha.
// node_attr gathered via full-line coalesced float4 loads staged to LDS (bf16);
// V-path depthwise product overwrites the x tile in place.
__global__ __launch_bounds__(256, 2) void conv_fused_kernel(
    const float* __restrict__ node_attr, const float* __restrict__ edge_attr,
    const float* __restrict__ edge_sh, const int* __restrict__ edge_index,
    const float* __restrict__ b1v, const float* __restrict__ b1k,
    const u16* __restrict__ wt, const u16* __restrict__ qw,
    u16* __restrict__ v_out, float* __restrict__ alpha)
{
  __shared__ __align__(16) u16 sC[64 * 40];    // fused [EA(16)|SH(16)|pad(8)]
  __shared__ __align__(16) u16 sX[64 * 136];   // x (bf16) -> t_v in place -> v result
  __shared__ __align__(16) u16 sTk[64 * 136];  // t_k
  __shared__ __align__(16) u16 sHv[64 * 72];   // relu(EA@W1v+b)
  __shared__ __align__(16) u16 sHk[64 * 72];   // relu(EA@W1k+b) -> k result
  uint4* sC4 = (uint4*)sC; u32* sC32 = (u32*)sC;
  uint4* sX4 = (uint4*)sX; u32* sX32 = (u32*)sX;
  uint4* sTk4 = (uint4*)sTk;
  uint4* sHv4 = (uint4*)sHv;
  uint4* sHk4 = (uint4*)sHk;
  const uint4* wt4 = (const uint4*)wt;

  const int tid = threadIdx.x;
  const int wv = tid >> 6, lane = tid & 63, lq = lane >> 4, ln = lane & 15;
  const int e0 = blockIdx.x * 64;
  const int nA = wv * 16 + ln, nB = (wv + 4) * 16 + ln;

  // dst q gather early (latency overlapped with staging/compute)
  const int el = tid >> 2, p = tid & 3;
  int dq = edge_index[NE + e0 + el]; if ((u32)dq >= NN) dq = 0;
  const uint4* qptr = (const uint4*)(qw + (size_t)dq * 64 + p * 16);
  uint4 q0 = qptr[0], q1 = qptr[1];

  // all weight fragments up-front (hoisted across the whole kernel)
  uint4 rW1V    = wt4[640 + nA * 5 + lq];
  uint4 rW1K    = wt4[4928 + nA * 5 + lq];
  uint4 rWangV0 = wt4[nA * 5 + lq],        rWangV1 = wt4[nB * 5 + lq];
  uint4 rWangK0 = wt4[4288 + nA * 5 + lq], rWangK1 = wt4[4288 + nB * 5 + lq];
  uint4 rWlinV[2][4], rWlinK[4], rW2V[2][2], rW2K[2];
#pragma unroll
  for (int ks = 0; ks < 4; ++ks) {
    rWlinV[0][ks] = wt4[960 + nA * 17 + ks * 4 + lq];
    rWlinV[1][ks] = wt4[960 + nB * 17 + ks * 4 + lq];
    rWlinK[ks]    = wt4[5248 + nA * 17 + ks * 4 + lq];
  }
#pragma unroll
  for (int ks = 0; ks < 2; ++ks) {
    rW2V[0][ks] = wt4[3136 + nA * 9 + ks * 4 + lq];
    rW2V[1][ks] = wt4[3136 + nB * 9 + ks * 4 + lq];
    rW2K[ks]    = wt4[6336 + nA * 9 + ks * 4 + lq];
  }
  float biasV = b1v[nA], biasK = b1k[nA];

  // stage fused EA|SH operand
  {
    int r = tid >> 2, kq = tid & 3;
    float4 ea = ((const float4*)(edge_attr + (size_t)(e0 + r) * 16))[kq];
    sC32[r * 20 + kq * 2]     = packb(ea.x, ea.y);
    sC32[r * 20 + kq * 2 + 1] = packb(ea.z, ea.w);
    float4 sh = ((const float4*)(edge_sh + (size_t)(e0 + r) * 16))[kq];
    sC32[r * 20 + 8 + kq * 2]     = packb(sh.x, sh.y);
    sC32[r * 20 + 8 + kq * 2 + 1] = packb(sh.z, sh.w);
  }
  // stage gathered node rows: 8 lanes per row-segment -> every global
  // transaction is a full 128B line. 8 float4 loads/thread total.
  {
    int g = tid >> 3, j = tid & 7;   // 32 groups x 8 lanes
#pragma unroll
    for (int rr = 0; rr < 2; ++rr) {
      int row = g + rr * 32;
      int s = edge_index[e0 + row]; if ((u32)s >= NN) s = 0;
      const float4* xp = (const float4*)(node_attr + (size_t)s * 128);
#pragma unroll
      for (int c = 0; c < 4; ++c) {
        float4 v = xp[c * 8 + j];
        sX32[row * 68 + c * 16 + j * 2]     = packb(v.x, v.y);
        sX32[row * 68 + c * 16 + j * 2 + 1] = packb(v.z, v.w);
      }
    }
  }
  __syncthreads();   // S1

  const f32x4 z4 = {0.f, 0.f, 0.f, 0.f};
  // ---- phase A: radial MLP hidden + depthwise SH products (6 MFMA / et)
#pragma unroll
  for (int et = 0; et < 4; ++et) {
    uint4 aC = sC4[(et * 16 + ln) * 5 + lq];
    f32x4 hv  = mf32(aC, rW1V, z4);
    f32x4 hk  = mf32(aC, rW1K, z4);
    f32x4 t0v = mf32(aC, rWangV0, z4);
    f32x4 t1v = mf32(aC, rWangV1, z4);
    f32x4 t0k = mf32(aC, rWangK0, z4);
    f32x4 t1k = mf32(aC, rWangK1, z4);
    int rowb = et * 16 + lq * 4;
#pragma unroll
    for (int r = 0; r < 4; ++r) {
      int row = rowb + r;
      float xA = b2f(sX[row * 136 + nA]);
      float xB = b2f(sX[row * 136 + nB]);
      sHv[row * 72 + nA]  = f2b(fmaxf(hv[r] + biasV, 0.f));
      sHk[row * 72 + nA]  = f2b(fmaxf(hk[r] + biasK, 0.f));
      sTk[row * 136 + nA] = f2b(t0k[r] * xA);
      sTk[row * 136 + nB] = f2b(t1k[r] * xB);
      sX[row * 136 + nA]  = f2b(t0v[r] * xA);   // t_v overwrites x in place
      sX[row * 136 + nB]  = f2b(t1v[r] * xB);
    }
  }
  __syncthreads();  // S2

  // ---- phase B: channel-mix (Wlin) and radial out (W2) for both paths
  f32x4 a1v[2][4], a2v[2][4], a1k[4], a2k[4];
#pragma unroll
  for (int et = 0; et < 4; ++et) {
    int ar = et * 16 + ln;
    f32x4 acc;
    acc = z4;
#pragma unroll
    for (int ks = 0; ks < 4; ++ks) acc = mf32(sX4[ar * 17 + ks * 4 + lq], rWlinV[0][ks], acc);
    a1v[0][et] = acc;
    acc = z4;
#pragma unroll
    for (int ks = 0; ks < 4; ++ks) acc = mf32(sX4[ar * 17 + ks * 4 + lq], rWlinV[1][ks], acc);
    a1v[1][et] = acc;
    acc = z4;
#pragma unroll
    for (int ks = 0; ks < 4; ++ks) acc = mf32(sTk4[ar * 17 + ks * 4 + lq], rWlinK[ks], acc);
    a1k[et] = acc;
    acc = z4;
#pragma unroll
    for (int ks = 0; ks < 2; ++ks) acc = mf32(sHv4[ar * 9 + ks * 4 + lq], rW2V[0][ks], acc);
    a2v[0][et] = acc;
    acc = z4;
#pragma unroll
    for (int ks = 0; ks < 2; ++ks) acc = mf32(sHv4[ar * 9 + ks * 4 + lq], rW2V[1][ks], acc);
    a2v[1][et] = acc;
    acc = z4;
#pragma unroll
    for (int ks = 0; ks < 2; ++ks) acc = mf32(sHk4[ar * 9 + ks * 4 + lq], rW2K[ks], acc);
    a2k[et] = acc;
  }
  __syncthreads();  // S3

  // ---- result staging: v into sX (pitch 136), k into sHk (pitch 72)
#pragma unroll
  for (int et = 0; et < 4; ++et) {
    int rowb = et * 16 + lq * 4;
#pragma unroll
    for (int r = 0; r < 4; ++r) {
      int row = rowb + r;
      sX[row * 136 + nA] = f2b(a1v[0][et][r] * a2v[0][et][r]);
      sX[row * 136 + nB] = f2b(a1v[1][et][r] * a2v[1][et][r]);
      sHk[row * 72 + nA] = f2b(a1k[et][r] * a2k[et][r]);
    }
  }
  __syncthreads();  // S4

  // coalesced v store
  {
    int row = tid >> 2, seg = tid & 3;
    uint4* gp = (uint4*)(v_out + (size_t)(e0 + row) * 128);
#pragma unroll
    for (int i = 0; i < 4; ++i) gp[seg * 4 + i] = sX4[row * 17 + seg * 4 + i];
  }
  // alpha = q . k  (bf16 dot2)
  {
    uint4 k0 = sHk4[el * 9 + p * 2];
    uint4 k1 = sHk4[el * 9 + p * 2 + 1];
    float a0 = 0.f, a1 = 0.f;
    a0 = dot2b(q0.x, k0.x, a0); a0 = dot2b(q0.y, k0.y, a0);
    a0 = dot2b(q0.z, k0.z, a0); a0 = dot2b(q0.w, k0.w, a0);
    a1 = dot2b(q1.x, k1.x, a1); a1 = dot2b(q1.y, k1.y, a1);
    a1 = dot2b(q1.z, k1.z, a1); a1 = dot2b(q1.w, k1.w, a1);
    ((float2*)(alpha + (size_t)(e0 + el) * 8))[p] = make_float2(a0, a1);
  }
}

// ---------------- CSR build
__global__ __launch_bounds__(256) void count_kernel(const int* __restrict__ edge_index,
                                                    int* __restrict__ counts)
{
  int e = blockIdx.x * 256 + threadIdx.x;
  if (e < NE) { int d = edge_index[NE + e]; if ((u32)d >= NN) d = 0; atomicAdd(&counts[d], 1); }
}

__global__ __launch_bounds__(1024) void scan_kernel(const int* __restrict__ counts,
                                                    int* __restrict__ row_ptr,
                                                    int* __restrict__ cursor)
{
  __shared__ int s[1024];
  int tid = threadIdx.x;
  int base = tid * STRIP;
  int sum = 0;
  for (int i = 0; i < STRIP; ++i) { int idx = base + i; sum += (idx < NN) ? counts[idx] : 0; }
  s[tid] = sum;
  __syncthreads();
  for (int off = 1; off < 1024; off <<= 1) {
    int v = s[tid];
    int add = (tid >= off) ? s[tid - off] : 0;
    __syncthreads();
    s[tid] = v + add;
    __syncthreads();
  }
  int running = (tid == 0) ? 0 : s[tid - 1];
  for (int i = 0; i < STRIP; ++i) {
    int idx = base + i;
    if (idx < NN) { row_ptr[idx] = running; cursor[idx] = running; running += counts[idx]; }
  }
  if (tid == 1023) row_ptr[NN] = running;
}

__global__ __launch_bounds__(256) void fill_kernel(const int* __restrict__ edge_index,
                                                   int* __restrict__ cursor,
                                                   int* __restrict__ edge_ids)
{
  int e = blockIdx.x * 256 + threadIdx.x;
  if (e < NE) {
    int dst = edge_index[NE + e]; if ((u32)dst >= NN) dst = 0;
    int pos = atomicAdd(&cursor[dst], 1);
    if ((u32)pos < NE) edge_ids[pos] = e;
  }
}

// ---------------- per-node single-pass online softmax + V gather (u32 loads,
// 4x unrolled) + MFMA @Wout epilogue. One wave per node, 16 nodes per block.
#define OUPD(aa, ww)                                                   \
  { float mn = fmaxf(m, (aa));                                         \
    float sc = __expf(m - mn);                                         \
    float pw = __expf((aa) - mn);                                      \
    l = l * sc + pw;                                                   \
    accA = accA * sc + pw * b2f_lo(ww);                                \
    accB = accB * sc + pw * b2f_hi(ww);                                \
    m = mn; }

__global__ __launch_bounds__(256) void out_kernel(
    const int* __restrict__ row_ptr, const int* __restrict__ edge_ids,
    const float* __restrict__ alpha, const u16* __restrict__ v_e,
    const u16* __restrict__ wt, float* __restrict__ out)
{
  __shared__ __align__(16) u16 sAgg[16 * 136];
  u32* sAgg32 = (u32*)sAgg;
  uint4* sAgg4 = (uint4*)sAgg;
  const uint4* wt4 = (const uint4*)wt;
  const u32* v32 = (const u32*)v_e;
  const int tid = threadIdx.x, wv = tid >> 6, lane = tid & 63, lq = lane >> 4, ln = lane & 15;
  const f32x4 z4 = {0.f, 0.f, 0.f, 0.f};
  uint4 rWT[2][4];
#pragma unroll
  for (int c = 0; c < 2; ++c) {
    int n = (wv * 2 + c) * 16 + ln;
#pragma unroll
    for (int ks = 0; ks < 4; ++ks) rWT[c][ks] = wt4[6912 + n * 17 + ks * 4 + lq];
  }
  const int hh = lane >> 3;   // head of cols {2*lane, 2*lane+1}
  const int grp = blockIdx.x;
#pragma unroll 1
  for (int i = 0; i < 4; ++i) {
    int n = grp * 16 + wv * 4 + i;
    int beg = row_ptr[n], end = row_ptr[n + 1];
    if (beg < 0) beg = 0; if (beg > NE) beg = NE;
    if (end < beg) end = beg; if (end > NE) end = NE;
    int deg = end - beg;
    float m = -3.0e38f, l = 0.f, accA = 0.f, accB = 0.f;
    int j = 0;
#pragma unroll 1
    for (; j + 4 <= deg; j += 4) {
      int e0 = edge_ids[beg + j],     e1 = edge_ids[beg + j + 1];
      int e2 = edge_ids[beg + j + 2], e3 = edge_ids[beg + j + 3];
      if ((u32)e0 >= NE) e0 = 0; if ((u32)e1 >= NE) e1 = 0;
      if ((u32)e2 >= NE) e2 = 0; if ((u32)e3 >= NE) e3 = 0;
      float a0 = alpha[(size_t)e0 * 8 + hh]; u32 w0 = v32[(size_t)e0 * 64 + lane];
      float a1 = alpha[(size_t)e1 * 8 + hh]; u32 w1 = v32[(size_t)e1 * 64 + lane];
      float a2 = alpha[(size_t)e2 * 8 + hh]; u32 w2 = v32[(size_t)e2 * 64 + lane];
      float a3 = alpha[(size_t)e3 * 8 + hh]; u32 w3 = v32[(size_t)e3 * 64 + lane];
      OUPD(a0, w0); OUPD(a1, w1); OUPD(a2, w2); OUPD(a3, w3);
    }
#pragma unroll 1
    for (; j < deg; ++j) {
      int e = edge_ids[beg + j]; if ((u32)e >= NE) e = 0;
      float a = alpha[(size_t)e * 8 + hh]; u32 w = v32[(size_t)e * 64 + lane];
      OUPD(a, w);
    }
    float inv = (l > 0.f) ? (1.f / l) : 0.f;
    accA *= inv; accB *= inv;
    sAgg32[(wv * 4 + i) * 68 + lane] = packb(accA, accB);
  }
  __syncthreads();
#pragma unroll
  for (int c = 0; c < 2; ++c) {
    f32x4 acc = z4;
#pragma unroll
    for (int ks = 0; ks < 4; ++ks) acc = mf32(sAgg4[ln * 17 + ks * 4 + lq], rWT[c][ks], acc);
    int col = (wv * 2 + c) * 16 + ln;
#pragma unroll
    for (int r = 0; r < 4; ++r)
      out[(size_t)(grp * 16 + lq * 4 + r) * 128 + col] = acc[r];
  }
}

extern "C" void kernel_launch(void* const* d_in, const int* in_sizes, int n_in,
                              void* d_out, int out_size, void* d_ws, size_t ws_size,
                              hipStream_t stream)
{
  const float* node_attr = (const float*)d_in[0];
  const float* edge_attr = (const float*)d_in[1];
  const float* edge_sh   = (const float*)d_in[2];
  const float* Wq        = (const float*)d_in[3];
  const float* Wang_k    = (const float*)d_in[4];
  const float* Wlin_k    = (const float*)d_in[5];
  const float* W1k       = (const float*)d_in[6];
  const float* b1k       = (const float*)d_in[7];
  const float* W2k       = (const float*)d_in[8];
  const float* Wang_v    = (const float*)d_in[9];
  const float* Wlin_v    = (const float*)d_in[10];
  const float* W1v       = (const float*)d_in[11];
  const float* b1v       = (const float*)d_in[12];
  const float* W2v       = (const float*)d_in[13];
  const float* Wdot      = (const float*)d_in[14];
  const float* Wout      = (const float*)d_in[15];
  const int* edge_index  = (const int*)d_in[16];
  float* out = (float*)d_out;

  char* ws = (char*)d_ws;
  u16*   v_e      = (u16*)(ws + 0);                 // E*128*2  = 204,800,000
  float* alpha    = (float*)(ws + 204800000);       // E*8*4    =  25,600,000
  u16*   qw       = (u16*)(ws + 230400000);         // N*64*2   =   6,400,000
  int*   counts   = (int*)(ws + 236800000);         // 200,064
  int*   row_ptr  = (int*)(ws + 237000064);         // 200,064
  int*   cursor   = (int*)(ws + 237200128);         // 200,064
  int*   edge_ids = (int*)(ws + 237400192);         // 3,200,000
  u16*   wt       = (u16*)(ws + 240600192);         // 162,816 -> total 240,763,008

  zero_kernel<<<dim3((NE + 255) / 256), dim3(256), 0, stream>>>(counts, edge_ids);
  prep_w_kernel<<<dim3((WT_TOTAL + 255) / 256), dim3(256), 0, stream>>>(
      Wang_v, W1v, Wlin_v, W2v, Wang_k, W1k, Wlin_k, W2k, Wout, Wq, Wdot, wt);
  qw_kernel<<<dim3((NN + 63) / 64), dim3(256), 0, stream>>>(node_attr, wt, qw);
  conv_fused_kernel<<<dim3(NE / 64), dim3(256), 0, stream>>>(
      node_attr, edge_attr, edge_sh, edge_index, b1v, b1k, wt, qw, v_e, alpha);
  count_kernel<<<dim3((NE + 255) / 256), dim3(256), 0, stream>>>(edge_index, counts);
  scan_kernel<<<dim3(1), dim3(1024), 0, stream>>>(counts, row_ptr, cursor);
  fill_kernel<<<dim3((NE + 255) / 256), dim3(256), 0, stream>>>(edge_index, cursor, edge_ids);
  out_kernel<<<dim3(3125), dim3(256), 0, stream>>>(row_ptr, edge_ids, alpha, v_e, wt, out);
}

// Round 4
// 673.504 us; speedup vs baseline: 1.0194x; 1.0172x over previous
//
#include <hip/hip_runtime.h>
#include <stdint.h>

#define NN 50000
#define NE 800000
#define STRIP 49   // ceil(NN/1024)

typedef unsigned int u32;
typedef uint16_t u16;

__device__ __forceinline__ float b2f(u16 u){ return __builtin_bit_cast(float, (u32)((u32)u << 16)); }
__device__ __forceinline__ float b2f_lo(u32 p){ return __builtin_bit_cast(float, p << 16); }
__device__ __forceinline__ float b2f_hi(u32 p){ return __builtin_bit_cast(float, p & 0xffff0000u); }
__device__ __forceinline__ u32 f2b_bits(float f){ u32 u = __builtin_bit_cast(u32, f); return (u + 0x7fffu + ((u >> 16) & 1u)) >> 16; }
__device__ __forceinline__ u16 f2b(float f){ return (u16)f2b_bits(f); }
__device__ __forceinline__ u32 packb(float lo, float hi){ return f2b_bits(lo) | (f2b_bits(hi) << 16); }

typedef __bf16 bf16x2 __attribute__((ext_vector_type(2)));
#if defined(__has_builtin)
#if __has_builtin(__builtin_amdgcn_fdot2_f32_bf16)
#define HAVE_DOT2_BUILTIN 1
#endif
#endif

#ifdef HAVE_DOT2_BUILTIN
__device__ __forceinline__ float dot2b(u32 a, u32 b, float c){
  return __builtin_amdgcn_fdot2_f32_bf16(__builtin_bit_cast(bf16x2, a),
                                         __builtin_bit_cast(bf16x2, b), c, false);
}
#else
__device__ __forceinline__ float dot2b(u32 a, u32 b, float c){
  c = fmaf(b2f_lo(a), b2f_lo(b), c);
  return fmaf(b2f_hi(a), b2f_hi(b), c);
}
#endif

// ---- MFMA plumbing ----
typedef __attribute__((ext_vector_type(8))) short short8;
typedef __attribute__((ext_vector_type(4))) float f32x4;
__device__ __forceinline__ f32x4 mf32(uint4 a, uint4 b, f32x4 c){
  return __builtin_amdgcn_mfma_f32_16x16x32_bf16(
      __builtin_bit_cast(short8, a), __builtin_bit_cast(short8, b), c, 0, 0, 0);
}

// pre-transposed weight layout offsets in u16 units (padded, zero-filled)
// Wang_* blocks hold data at k in [16,32) (SH = upper half of fused [EA|SH]
// K=32 operand); W1_* keep data at k in [0,16).
#define OFF_WANG_V 0        // [128][40]
#define OFF_W1_V   5120     // [64][40]
#define OFF_WLIN_V 7680     // [128][136]
#define OFF_W2_V   25088    // [128][72]
#define OFF_WANG_K 34304    // [128][40]
#define OFF_W1_K   39424    // [64][40]
#define OFF_WLIN_K 41984    // [64][136]
#define OFF_W2_K   50688    // [64][72]
#define OFF_WOUT   55296    // [128][136]
#define OFF_WQD    72704    // [64][136]  (Wq @ blockdiag(Wdot))^T
#define WT_TOTAL   81408

__global__ __launch_bounds__(256) void zero_kernel(int* __restrict__ counts,
                                                   int* __restrict__ edge_ids)
{
  int i = blockIdx.x * 256 + threadIdx.x;
  if (i < NN) counts[i] = 0;
  if (i < NE) edge_ids[i] = 0;
}

// ---------------- one-time weight transpose/pad/bf16 prep
__global__ __launch_bounds__(256) void prep_w_kernel(
    const float* __restrict__ Wang_v, const float* __restrict__ W1_v,
    const float* __restrict__ Wlin_v, const float* __restrict__ W2_v,
    const float* __restrict__ Wang_k, const float* __restrict__ W1_k,
    const float* __restrict__ Wlin_k, const float* __restrict__ W2_k,
    const float* __restrict__ Wout, const float* __restrict__ Wq,
    const float* __restrict__ Wdot,
    u16* __restrict__ wt)
{
  int idx = blockIdx.x * 256 + threadIdx.x;
  if (idx >= WT_TOTAL) return;
  float val = 0.f;
  if (idx < OFF_W1_V) {
    int l = idx - OFF_WANG_V, n = l / 40, k = l % 40;
    if (k >= 16 && k < 32) val = Wang_v[n * 16 + (k - 16)];
  } else if (idx < OFF_WLIN_V) {
    int l = idx - OFF_W1_V, n = l / 40, k = l % 40;
    if (k < 16) val = W1_v[k * 64 + n];
  } else if (idx < OFF_W2_V) {
    int l = idx - OFF_WLIN_V, n = l / 136, k = l % 136;
    if (k < 128) val = Wlin_v[k * 128 + n];
  } else if (idx < OFF_WANG_K) {
    int l = idx - OFF_W2_V, n = l / 72, k = l % 72;
    if (k < 64) val = W2_v[k * 128 + n];
  } else if (idx < OFF_W1_K) {
    int l = idx - OFF_WANG_K, n = l / 40, k = l % 40;
    if (k >= 16 && k < 32) val = Wang_k[n * 16 + (k - 16)];
  } else if (idx < OFF_WLIN_K) {
    int l = idx - OFF_W1_K, n = l / 40, k = l % 40;
    if (k < 16) val = W1_k[k * 64 + n];
  } else if (idx < OFF_W2_K) {
    int l = idx - OFF_WLIN_K, n = l / 136, k = l % 136;
    if (k < 128) val = Wlin_k[k * 64 + n];
  } else if (idx < OFF_WOUT) {
    int l = idx - OFF_W2_K, n = l / 72, k = l % 72;
    if (k < 64) val = W2_k[k * 64 + n];
  } else if (idx < OFF_WQD) {                // WoutT: B^T[n][k] = Wout[k*128+n]
    int l = idx - OFF_WOUT, n = l / 136, k = l % 136;
    if (k < 128) val = Wout[k * 128 + n];
  } else {                                   // WqdT[n][k] = sum_i Wq[k,h*8+i]*Wdot[i,r]
    int l = idx - OFF_WQD, n = l / 136, k = l % 136;
    if (k < 128) {
      int h = n >> 3, r = n & 7;
      float s = 0.f;
#pragma unroll
      for (int i = 0; i < 8; ++i) s += Wq[k * 64 + h * 8 + i] * Wdot[i * 8 + r];
      val = s;
    }
  }
  wt[idx] = f2b(val);
}

// ---------------- qw = node_attr @ Wqd, MFMA, 64 nodes/block
__global__ __launch_bounds__(256) void qw_kernel(const float* __restrict__ node_attr,
                                                 const u16* __restrict__ wt,
                                                 u16* __restrict__ qw)
{
  __shared__ __align__(16) u16 sX[64 * 136];
  uint4* sX4 = (uint4*)sX;
  u32* sX32 = (u32*)sX;
  const uint4* wt4 = (const uint4*)wt;
  const int tid = threadIdx.x, wv = tid >> 6, lane = tid & 63, lq = lane >> 4, ln = lane & 15;
  const int n0 = blockIdx.x * 64;
  uint4 rB[4];
#pragma unroll
  for (int ks = 0; ks < 4; ++ks) rB[ks] = wt4[9088 + (wv * 16 + ln) * 17 + ks * 4 + lq];
  {
    int row = tid >> 2, q4 = tid & 3;
    int n = n0 + row;
    bool valid = n < NN;
    const float4* xp = (const float4*)(node_attr + (size_t)(valid ? n : 0) * 128);
#pragma unroll
    for (int i = 0; i < 8; ++i) {
      float4 v = valid ? xp[q4 * 8 + i] : make_float4(0.f, 0.f, 0.f, 0.f);
      sX32[row * 68 + (q4 * 8 + i) * 2]     = packb(v.x, v.y);
      sX32[row * 68 + (q4 * 8 + i) * 2 + 1] = packb(v.z, v.w);
    }
  }
  __syncthreads();
  const f32x4 z4 = {0.f, 0.f, 0.f, 0.f};
  int col = wv * 16 + ln;
#pragma unroll
  for (int et = 0; et < 4; ++et) {
    f32x4 acc = z4;
#pragma unroll
    for (int ks = 0; ks < 4; ++ks) acc = mf32(sX4[(et * 16 + ln) * 17 + ks * 4 + lq], rB[ks], acc);
#pragma unroll
    for (int r = 0; r < 4; ++r) {
      int rr = n0 + et * 16 + lq * 4 + r;
      if (rr < NN) qw[(size_t)rr * 64 + col] = f2b(acc[r]);
    }
  }
}

// ---------------- fused MFMA conv (single pass) + alpha.
// MFMA operands SWAPPED (A=weights, B=edge tiles): each thread owns 4
// consecutive channels of one edge -> all LDS result traffic is b64, not u16.
// Fragment addresses are unchanged by the swap (weight [n][k] rows serve as
// A-fragments; staged [edge][k] tiles serve as B-fragments at the same
// addresses as before).
__global__ __launch_bounds__(256, 2) void conv_fused_kernel(
    const float* __restrict__ node_attr, const float* __restrict__ edge_attr,
    const float* __restrict__ edge_sh, const int* __restrict__ edge_index,
    const float* __restrict__ b1v, const float* __restrict__ b1k,
    const u16* __restrict__ wt, const u16* __restrict__ qw,
    u16* __restrict__ v_out, float* __restrict__ alpha)
{
  __shared__ __align__(16) u16 sC[64 * 40];    // fused [EA(16)|SH(16)|pad(8)]
  __shared__ __align__(16) u16 sX[64 * 136];   // x (bf16) -> t_v in place -> v result
  __shared__ __align__(16) u16 sTk[64 * 136];  // t_k
  __shared__ __align__(16) u16 sHv[64 * 72];   // relu(EA@W1v+b)
  __shared__ __align__(16) u16 sHk[64 * 72];   // relu(EA@W1k+b) -> k result
  uint4* sC4 = (uint4*)sC; u32* sC32 = (u32*)sC;
  uint4* sX4 = (uint4*)sX; u32* sX32 = (u32*)sX;
  uint4* sTk4 = (uint4*)sTk;
  uint4* sHv4 = (uint4*)sHv;
  uint4* sHk4 = (uint4*)sHk;
  const uint4* wt4 = (const uint4*)wt;

  const int tid = threadIdx.x;
  const int wv = tid >> 6, lane = tid & 63, lq = lane >> 4, ln = lane & 15;
  const int e0 = blockIdx.x * 64;
  const int nA = wv * 16 + ln, nB = (wv + 4) * 16 + ln;
  const int cb = wv * 16 + 4 * lq;     // channel base owned by this thread

  // dst q gather early (latency overlapped with staging/compute)
  const int el = tid >> 2, p = tid & 3;
  int dq = edge_index[NE + e0 + el]; if ((u32)dq >= NN) dq = 0;
  const uint4* qptr = (const uint4*)(qw + (size_t)dq * 64 + p * 16);
  uint4 q0 = qptr[0], q1 = qptr[1];

  // weight fragments (A-operands after swap; same addresses as before)
  uint4 rW1V    = wt4[640 + nA * 5 + lq];
  uint4 rW1K    = wt4[4928 + nA * 5 + lq];
  uint4 rWangV0 = wt4[nA * 5 + lq],        rWangV1 = wt4[nB * 5 + lq];
  uint4 rWangK0 = wt4[4288 + nA * 5 + lq], rWangK1 = wt4[4288 + nB * 5 + lq];
  uint4 rWlinV[2][4], rWlinK[4], rW2V[2][2], rW2K[2];
#pragma unroll
  for (int ks = 0; ks < 4; ++ks) {
    rWlinV[0][ks] = wt4[960 + nA * 17 + ks * 4 + lq];
    rWlinV[1][ks] = wt4[960 + nB * 17 + ks * 4 + lq];
    rWlinK[ks]    = wt4[5248 + nA * 17 + ks * 4 + lq];
  }
#pragma unroll
  for (int ks = 0; ks < 2; ++ks) {
    rW2V[0][ks] = wt4[3136 + nA * 9 + ks * 4 + lq];
    rW2V[1][ks] = wt4[3136 + nB * 9 + ks * 4 + lq];
    rW2K[ks]    = wt4[6336 + nA * 9 + ks * 4 + lq];
  }
  float4 bV = *(const float4*)(b1v + cb);
  float4 bK = *(const float4*)(b1k + cb);

  // stage fused EA|SH operand
  {
    int r = tid >> 2, kq = tid & 3;
    float4 ea = ((const float4*)(edge_attr + (size_t)(e0 + r) * 16))[kq];
    *(uint2*)(sC32 + r * 20 + kq * 2) = make_uint2(packb(ea.x, ea.y), packb(ea.z, ea.w));
    float4 sh = ((const float4*)(edge_sh + (size_t)(e0 + r) * 16))[kq];
    *(uint2*)(sC32 + r * 20 + 8 + kq * 2) = make_uint2(packb(sh.x, sh.y), packb(sh.z, sh.w));
  }
  // stage gathered node rows: 8 lanes per row-segment -> full 128B lines
  {
    int g = tid >> 3, j = tid & 7;   // 32 groups x 8 lanes
#pragma unroll
    for (int rr = 0; rr < 2; ++rr) {
      int row = g + rr * 32;
      int s = edge_index[e0 + row]; if ((u32)s >= NN) s = 0;
      const float4* xp = (const float4*)(node_attr + (size_t)s * 128);
#pragma unroll
      for (int c = 0; c < 4; ++c) {
        float4 v = xp[c * 8 + j];
        *(uint2*)(sX32 + row * 68 + c * 16 + j * 2) =
            make_uint2(packb(v.x, v.y), packb(v.z, v.w));
      }
    }
  }
  __syncthreads();   // S1

  const f32x4 z4 = {0.f, 0.f, 0.f, 0.f};
  // ---- phase A: radial MLP hidden + depthwise SH products (6 MFMA / et)
  // D[channel][edge]: thread owns channels cb..cb+3 of edge et*16+ln.
#pragma unroll
  for (int et = 0; et < 4; ++et) {
    uint4 aC = sC4[(et * 16 + ln) * 5 + lq];
    f32x4 hv  = mf32(rW1V, aC, z4);
    f32x4 hk  = mf32(rW1K, aC, z4);
    f32x4 t0v = mf32(rWangV0, aC, z4);
    f32x4 t1v = mf32(rWangV1, aC, z4);
    f32x4 t0k = mf32(rWangK0, aC, z4);
    f32x4 t1k = mf32(rWangK1, aC, z4);
    const int edge = et * 16 + ln;
    u16* xr = sX + edge * 136 + cb;
    uint2 xa = *(const uint2*)xr;
    uint2 xb = *(const uint2*)(xr + 64);
    float x0 = b2f_lo(xa.x), x1 = b2f_hi(xa.x), x2 = b2f_lo(xa.y), x3 = b2f_hi(xa.y);
    float y0 = b2f_lo(xb.x), y1 = b2f_hi(xb.x), y2 = b2f_lo(xb.y), y3 = b2f_hi(xb.y);
    *(uint2*)xr = make_uint2(packb(t0v[0] * x0, t0v[1] * x1),
                             packb(t0v[2] * x2, t0v[3] * x3));
    *(uint2*)(xr + 64) = make_uint2(packb(t1v[0] * y0, t1v[1] * y1),
                                    packb(t1v[2] * y2, t1v[3] * y3));
    u16* tkr = sTk + edge * 136 + cb;
    *(uint2*)tkr = make_uint2(packb(t0k[0] * x0, t0k[1] * x1),
                              packb(t0k[2] * x2, t0k[3] * x3));
    *(uint2*)(tkr + 64) = make_uint2(packb(t1k[0] * y0, t1k[1] * y1),
                                     packb(t1k[2] * y2, t1k[3] * y3));
    *(uint2*)(sHv + edge * 72 + cb) = make_uint2(
        packb(fmaxf(hv[0] + bV.x, 0.f), fmaxf(hv[1] + bV.y, 0.f)),
        packb(fmaxf(hv[2] + bV.z, 0.f), fmaxf(hv[3] + bV.w, 0.f)));
    *(uint2*)(sHk + edge * 72 + cb) = make_uint2(
        packb(fmaxf(hk[0] + bK.x, 0.f), fmaxf(hk[1] + bK.y, 0.f)),
        packb(fmaxf(hk[2] + bK.z, 0.f), fmaxf(hk[3] + bK.w, 0.f)));
  }
  __syncthreads();  // S2

  // ---- phase B: channel-mix (Wlin) and radial out (W2), swapped operands
  f32x4 a1v0[4], a1v1[4], a1k[4], a2v0[4], a2v1[4], a2k[4];
#pragma unroll
  for (int et = 0; et < 4; ++et) {
    const int er = et * 16 + ln;
    f32x4 acc0 = z4, acc1 = z4, acck = z4;
#pragma unroll
    for (int ks = 0; ks < 4; ++ks) {
      uint4 tb = sX4[er * 17 + ks * 4 + lq];
      acc0 = mf32(rWlinV[0][ks], tb, acc0);
      acc1 = mf32(rWlinV[1][ks], tb, acc1);
      acck = mf32(rWlinK[ks], sTk4[er * 17 + ks * 4 + lq], acck);
    }
    a1v0[et] = acc0; a1v1[et] = acc1; a1k[et] = acck;
    f32x4 b0 = z4, b1 = z4, bk = z4;
#pragma unroll
    for (int ks = 0; ks < 2; ++ks) {
      uint4 hb = sHv4[er * 9 + ks * 4 + lq];
      b0 = mf32(rW2V[0][ks], hb, b0);
      b1 = mf32(rW2V[1][ks], hb, b1);
      bk = mf32(rW2K[ks], sHk4[er * 9 + ks * 4 + lq], bk);
    }
    a2v0[et] = b0; a2v1[et] = b1; a2k[et] = bk;
  }
  __syncthreads();  // S3

  // ---- result staging: all b64 writes (thread owns 4 consecutive channels)
#pragma unroll
  for (int et = 0; et < 4; ++et) {
    const int edge = et * 16 + ln;
    u16* vr = sX + edge * 136 + cb;
    *(uint2*)vr = make_uint2(
        packb(a1v0[et][0] * a2v0[et][0], a1v0[et][1] * a2v0[et][1]),
        packb(a1v0[et][2] * a2v0[et][2], a1v0[et][3] * a2v0[et][3]));
    *(uint2*)(vr + 64) = make_uint2(
        packb(a1v1[et][0] * a2v1[et][0], a1v1[et][1] * a2v1[et][1]),
        packb(a1v1[et][2] * a2v1[et][2], a1v1[et][3] * a2v1[et][3]));
    *(uint2*)(sHk + edge * 72 + cb) = make_uint2(
        packb(a1k[et][0] * a2k[et][0], a1k[et][1] * a2k[et][1]),
        packb(a1k[et][2] * a2k[et][2], a1k[et][3] * a2k[et][3]));
  }
  __syncthreads();  // S4

  // coalesced v store
  {
    int row = tid >> 2, seg = tid & 3;
    uint4* gp = (uint4*)(v_out + (size_t)(e0 + row) * 128);
#pragma unroll
    for (int i = 0; i < 4; ++i) gp[seg * 4 + i] = sX4[row * 17 + seg * 4 + i];
  }
  // alpha = q . k  (bf16 dot2)
  {
    uint4 k0 = sHk4[el * 9 + p * 2];
    uint4 k1 = sHk4[el * 9 + p * 2 + 1];
    float a0 = 0.f, a1 = 0.f;
    a0 = dot2b(q0.x, k0.x, a0); a0 = dot2b(q0.y, k0.y, a0);
    a0 = dot2b(q0.z, k0.z, a0); a0 = dot2b(q0.w, k0.w, a0);
    a1 = dot2b(q1.x, k1.x, a1); a1 = dot2b(q1.y, k1.y, a1);
    a1 = dot2b(q1.z, k1.z, a1); a1 = dot2b(q1.w, k1.w, a1);
    ((float2*)(alpha + (size_t)(e0 + el) * 8))[p] = make_float2(a0, a1);
  }
}

// ---------------- CSR build
__global__ __launch_bounds__(256) void count_kernel(const int* __restrict__ edge_index,
                                                    int* __restrict__ counts)
{
  int e = blockIdx.x * 256 + threadIdx.x;
  if (e < NE) { int d = edge_index[NE + e]; if ((u32)d >= NN) d = 0; atomicAdd(&counts[d], 1); }
}

__global__ __launch_bounds__(1024) void scan_kernel(const int* __restrict__ counts,
                                                    int* __restrict__ row_ptr,
                                                    int* __restrict__ cursor)
{
  __shared__ int s[1024];
  int tid = threadIdx.x;
  int base = tid * STRIP;
  int sum = 0;
  for (int i = 0; i < STRIP; ++i) { int idx = base + i; sum += (idx < NN) ? counts[idx] : 0; }
  s[tid] = sum;
  __syncthreads();
  for (int off = 1; off < 1024; off <<= 1) {
    int v = s[tid];
    int add = (tid >= off) ? s[tid - off] : 0;
    __syncthreads();
    s[tid] = v + add;
    __syncthreads();
  }
  int running = (tid == 0) ? 0 : s[tid - 1];
  for (int i = 0; i < STRIP; ++i) {
    int idx = base + i;
    if (idx < NN) { row_ptr[idx] = running; cursor[idx] = running; running += counts[idx]; }
  }
  if (tid == 1023) row_ptr[NN] = running;
}

__global__ __launch_bounds__(256) void fill_kernel(const int* __restrict__ edge_index,
                                                   int* __restrict__ cursor,
                                                   int* __restrict__ edge_ids)
{
  int e = blockIdx.x * 256 + threadIdx.x;
  if (e < NE) {
    int dst = edge_index[NE + e]; if ((u32)dst >= NN) dst = 0;
    int pos = atomicAdd(&cursor[dst], 1);
    if ((u32)pos < NE) edge_ids[pos] = e;
  }
}

// ---------------- per-node single-pass online softmax + V gather (u32 loads,
// 4x unrolled) + MFMA @Wout epilogue. One wave per node, 16 nodes per block.
#define OUPD(aa, ww)                                                   \
  { float mn = fmaxf(m, (aa));                                         \
    float sc = __expf(m - mn);                                         \
    float pw = __expf((aa) - mn);                                      \
    l = l * sc + pw;                                                   \
    accA = accA * sc + pw * b2f_lo(ww);                                \
    accB = accB * sc + pw * b2f_hi(ww);                                \
    m = mn; }

__global__ __launch_bounds__(256) void out_kernel(
    const int* __restrict__ row_ptr, const int* __restrict__ edge_ids,
    const float* __restrict__ alpha, const u16* __restrict__ v_e,
    const u16* __restrict__ wt, float* __restrict__ out)
{
  __shared__ __align__(16) u16 sAgg[16 * 136];
  u32* sAgg32 = (u32*)sAgg;
  uint4* sAgg4 = (uint4*)sAgg;
  const uint4* wt4 = (const uint4*)wt;
  const u32* v32 = (const u32*)v_e;
  const int tid = threadIdx.x, wv = tid >> 6, lane = tid & 63, lq = lane >> 4, ln = lane & 15;
  const f32x4 z4 = {0.f, 0.f, 0.f, 0.f};
  uint4 rWT[2][4];
#pragma unroll
  for (int c = 0; c < 2; ++c) {
    int n = (wv * 2 + c) * 16 + ln;
#pragma unroll
    for (int ks = 0; ks < 4; ++ks) rWT[c][ks] = wt4[6912 + n * 17 + ks * 4 + lq];
  }
  const int hh = lane >> 3;   // head of cols {2*lane, 2*lane+1}
  const int grp = blockIdx.x;
#pragma unroll 1
  for (int i = 0; i < 4; ++i) {
    int n = grp * 16 + wv * 4 + i;
    int beg = row_ptr[n], end = row_ptr[n + 1];
    if (beg < 0) beg = 0; if (beg > NE) beg = NE;
    if (end < beg) end = beg; if (end > NE) end = NE;
    int deg = end - beg;
    float m = -3.0e38f, l = 0.f, accA = 0.f, accB = 0.f;
    int j = 0;
#pragma unroll 1
    for (; j + 4 <= deg; j += 4) {
      int e0 = edge_ids[beg + j],     e1 = edge_ids[beg + j + 1];
      int e2 = edge_ids[beg + j + 2], e3 = edge_ids[beg + j + 3];
      if ((u32)e0 >= NE) e0 = 0; if ((u32)e1 >= NE) e1 = 0;
      if ((u32)e2 >= NE) e2 = 0; if ((u32)e3 >= NE) e3 = 0;
      float a0 = alpha[(size_t)e0 * 8 + hh]; u32 w0 = v32[(size_t)e0 * 64 + lane];
      float a1 = alpha[(size_t)e1 * 8 + hh]; u32 w1 = v32[(size_t)e1 * 64 + lane];
      float a2 = alpha[(size_t)e2 * 8 + hh]; u32 w2 = v32[(size_t)e2 * 64 + lane];
      float a3 = alpha[(size_t)e3 * 8 + hh]; u32 w3 = v32[(size_t)e3 * 64 + lane];
      OUPD(a0, w0); OUPD(a1, w1); OUPD(a2, w2); OUPD(a3, w3);
    }
#pragma unroll 1
    for (; j < deg; ++j) {
      int e = edge_ids[beg + j]; if ((u32)e >= NE) e = 0;
      float a = alpha[(size_t)e * 8 + hh]; u32 w = v32[(size_t)e * 64 + lane];
      OUPD(a, w);
    }
    float inv = (l > 0.f) ? (1.f / l) : 0.f;
    accA *= inv; accB *= inv;
    sAgg32[(wv * 4 + i) * 68 + lane] = packb(accA, accB);
  }
  __syncthreads();
#pragma unroll
  for (int c = 0; c < 2; ++c) {
    f32x4 acc = z4;
#pragma unroll
    for (int ks = 0; ks < 4; ++ks) acc = mf32(sAgg4[ln * 17 + ks * 4 + lq], rWT[c][ks], acc);
    int col = (wv * 2 + c) * 16 + ln;
#pragma unroll
    for (int r = 0; r < 4; ++r)
      out[(size_t)(grp * 16 + lq * 4 + r) * 128 + col] = acc[r];
  }
}

extern "C" void kernel_launch(void* const* d_in, const int* in_sizes, int n_in,
                              void* d_out, int out_size, void* d_ws, size_t ws_size,
                              hipStream_t stream)
{
  const float* node_attr = (const float*)d_in[0];
  const float* edge_attr = (const float*)d_in[1];
  const float* edge_sh   = (const float*)d_in[2];
  const float* Wq        = (const float*)d_in[3];
  const float* Wang_k    = (const float*)d_in[4];
  const float* Wlin_k    = (const float*)d_in[5];
  const float* W1k       = (const float*)d_in[6];
  const float* b1k       = (const float*)d_in[7];
  const float* W2k       = (const float*)d_in[8];
  const float* Wang_v    = (const float*)d_in[9];
  const float* Wlin_v    = (const float*)d_in[10];
  const float* W1v       = (const float*)d_in[11];
  const float* b1v       = (const float*)d_in[12];
  const float* W2v       = (const float*)d_in[13];
  const float* Wdot      = (const float*)d_in[14];
  const float* Wout      = (const float*)d_in[15];
  const int* edge_index  = (const int*)d_in[16];
  float* out = (float*)d_out;

  char* ws = (char*)d_ws;
  u16*   v_e      = (u16*)(ws + 0);                 // E*128*2  = 204,800,000
  float* alpha    = (float*)(ws + 204800000);       // E*8*4    =  25,600,000
  u16*   qw       = (u16*)(ws + 230400000);         // N*64*2   =   6,400,000
  int*   counts   = (int*)(ws + 236800000);         // 200,064
  int*   row_ptr  = (int*)(ws + 237000064);         // 200,064
  int*   cursor   = (int*)(ws + 237200128);         // 200,064
  int*   edge_ids = (int*)(ws + 237400192);         // 3,200,000
  u16*   wt       = (u16*)(ws + 240600192);         // 162,816 -> total 240,763,008

  zero_kernel<<<dim3((NE + 255) / 256), dim3(256), 0, stream>>>(counts, edge_ids);
  prep_w_kernel<<<dim3((WT_TOTAL + 255) / 256), dim3(256), 0, stream>>>(
      Wang_v, W1v, Wlin_v, W2v, Wang_k, W1k, Wlin_k, W2k, Wout, Wq, Wdot, wt);
  qw_kernel<<<dim3((NN + 63) / 64), dim3(256), 0, stream>>>(node_attr, wt, qw);
  conv_fused_kernel<<<dim3(NE / 64), dim3(256), 0, stream>>>(
      node_attr, edge_attr, edge_sh, edge_index, b1v, b1k, wt, qw, v_e, alpha);
  count_kernel<<<dim3((NE + 255) / 256), dim3(256), 0, stream>>>(edge_index, counts);
  scan_kernel<<<dim3(1), dim3(1024), 0, stream>>>(counts, row_ptr, cursor);
  fill_kernel<<<dim3((NE + 255) / 256), dim3(256), 0, stream>>>(edge_index, cursor, edge_ids);
  out_kernel<<<dim3(3125), dim3(256), 0, stream>>>(row_ptr, edge_ids, alpha, v_e, wt, out);
}